// Round 8
// baseline (63.145 us; speedup 1.0000x reference)
//
#include <hip/hip_runtime.h>

// GCLSTM (K=1 Cheb, H0=C0=0) fused kernel for MI355X — v8.
// Math: i=sig(x@Wi+bi'), t=tanh(x@Wc+bc'), C=i*t, o=sig(x@Wo+bo'+wco*C),
//       out = (o*tanh(C)) @ fcW + fcb.  edge_index/batch/Wg_*/W_f unused.
// v8: latency amortization. T=2 tiles (64 rows) per wave; x for BOTH tiles
//     loaded in one burst at wave start (tile-1 HBM latency hidden under
//     tile-0 compute); phases fully unrolled for cross-tile ILP. No LDS at
//     all (v4 vs v7 proved weight-LDS neutral; removes barrier + LDS cap).
//     Weights/af/bias from L1/L2 (universal addresses, hot after warmup).
//     launch_bounds(256,3): ~170 VGPR budget, no spill; supply-capped occ.

typedef __attribute__((ext_vector_type(8))) short short8;
typedef __attribute__((ext_vector_type(4))) float f32x4;

#define N_ROWS 200000
#define IN_DIM 64
#define HID 128
#define OUT_DIM 64

// ws layout (bytes)
#define WFRAG_ELEMS (24 * 2 * 64 * 8)   // 24576 bf16 = 49152 B
#define FCFRAG_OFF  49152               // WFRAG_ELEMS*2
#define FCFRAG_ELEMS (4 * 4 * 64 * 8)   // 8192 bf16 = 16384 B
#define BIAS_OFF    65536               // floats: bi[128],bc[128],bo[128],wco[128] (h-permuted), fcb[64]

__device__ __forceinline__ short f2bf(float f) {
  unsigned u = __float_as_uint(f);
  u += 0x7FFFu + ((u >> 16) & 1u);   // RNE (repack only)
  return (short)(u >> 16);
}
__device__ __forceinline__ unsigned cvt_pk_bf16(float lo, float hi) {
  unsigned r;
  asm("v_cvt_pk_bf16_f32 %0, %1, %2" : "=v"(r) : "v"(lo), "v"(hi));
  return r;
}
__device__ __forceinline__ float fexp2(float z) { return __builtin_amdgcn_exp2f(z); }
__device__ __forceinline__ float frcp(float z)  { return __builtin_amdgcn_rcpf(z); }
__device__ __forceinline__ float fsigmoid(float z) {
  return frcp(1.0f + fexp2(-1.44269504f * z));
}
__device__ __forceinline__ float ftanh(float z) {
  return 1.0f - 2.0f * frcp(1.0f + fexp2(2.88539008f * z));
}
// permuted global hid for GEMM1 tile g (0..7), D-row d (0..15)
__device__ __forceinline__ int hperm(int g, int d) {
  return 32 * (g >> 1) + 2 * (g & 1) + 8 * (d >> 2) + 4 * ((d >> 1) & 1) + (d & 1);
}

// ---- repack: weights -> bf16 MFMA A-fragments, biases -> combined fp32 ----
__global__ void repack_kernel(const float* __restrict__ W_i, const float* __restrict__ W_c,
                              const float* __restrict__ W_o, const float* __restrict__ fc_W,
                              const float* __restrict__ bg_i, const float* __restrict__ bg_c,
                              const float* __restrict__ bg_o,
                              const float* __restrict__ b_i, const float* __restrict__ b_c,
                              const float* __restrict__ b_o, const float* __restrict__ wc_o,
                              const float* __restrict__ fc_b,
                              short* __restrict__ wfrag, short* __restrict__ fcfrag,
                              float* __restrict__ bias) {
  int tid = blockIdx.x * blockDim.x + threadIdx.x;
  const int total1 = WFRAG_ELEMS;
  const int total2 = FCFRAG_ELEMS;
  for (int e = tid; e < total1 + total2 + HID + OUT_DIM; e += gridDim.x * blockDim.x) {
    if (e < total1) {
      // A-frag of GEMM1: A row (=D row) cidx of tile g, k=32s+8q+j, PERMUTED h
      int j = e & 7, lane = (e >> 3) & 63, s = (e >> 9) & 1, t = e >> 10;
      int q = lane >> 4, cidx = lane & 15;
      int gate = t >> 3;                       // 0:W_i 1:W_c 2:W_o
      int g = t & 7;
      int h = hperm(g, cidx);
      int feat = 32 * s + 8 * q + j;
      const float* W = (gate == 0) ? W_i : ((gate == 1) ? W_c : W_o);
      wfrag[e] = f2bf(W[feat * HID + h]);
    } else if (e < total1 + total2) {
      // A-frag of GEMM2: A = fc_W^T (64x128), STANDARD hid = 32s+8q+j
      int e2 = e - total1;
      int j = e2 & 7, lane = (e2 >> 3) & 63, s = (e2 >> 9) & 3, t = e2 >> 11;
      int q = lane >> 4, cidx = lane & 15;
      int od = 16 * t + cidx;
      int hid = 32 * s + 8 * q + j;
      fcfrag[e2] = f2bf(fc_W[hid * OUT_DIM + od]);
    } else if (e < total1 + total2 + HID) {
      int p = e - total1 - total2;             // permuted storage index g*16+d
      int h = hperm(p >> 4, p & 15);
      bias[p]           = bg_i[h] + b_i[h];
      bias[HID + p]     = bg_c[h] + b_c[h];
      bias[2 * HID + p] = bg_o[h] + b_o[h];
      bias[3 * HID + p] = wc_o[h];
    } else {
      int h2 = e - total1 - total2 - HID;
      bias[4 * HID + h2] = fc_b[h2];
    }
  }
}

// ---- fused main kernel: 64 rows (2 tiles) per wave, no LDS, no barriers ----
__global__ __launch_bounds__(256, 3) void gclstm_fused(
    const float* __restrict__ x, const short* __restrict__ wfrag,
    const short* __restrict__ fcfrag, const float* __restrict__ bias,
    float* __restrict__ out) {
  const int lane = threadIdx.x & 63;
  const int wid = (blockIdx.x * blockDim.x + threadIdx.x) >> 6;
  if (wid >= N_ROWS / 64) return;        // 200000/64 = 3125 waves, exact
  const int q = lane >> 4, c = lane & 15;
  const size_t rbase = (size_t)wid * 64;
  const short* wf = wfrag + lane * 8;
  const short* ff = fcfrag + lane * 8;

  union U { unsigned u[4]; short8 s8; };

  // ---- burst-load x for BOTH tiles, then convert (t1 latency hidden) ----
  short8 bx[2][2][2];                    // [tile][m][sk]
  {
    f32x4 raw[2][2][2][2];               // [tile][m][sk][half]
#pragma unroll
    for (int tt = 0; tt < 2; ++tt)
#pragma unroll
      for (int m = 0; m < 2; ++m) {
        const float* xr = x + (rbase + tt * 32 + 16 * m + c) * IN_DIM + 8 * q;
#pragma unroll
        for (int sk = 0; sk < 2; ++sk) {
          raw[tt][m][sk][0] = *(const f32x4*)(xr + 32 * sk);
          raw[tt][m][sk][1] = *(const f32x4*)(xr + 32 * sk + 4);
        }
      }
#pragma unroll
    for (int tt = 0; tt < 2; ++tt)
#pragma unroll
      for (int m = 0; m < 2; ++m)
#pragma unroll
        for (int sk = 0; sk < 2; ++sk) {
          U v;
          v.u[0] = cvt_pk_bf16(raw[tt][m][sk][0][0], raw[tt][m][sk][0][1]);
          v.u[1] = cvt_pk_bf16(raw[tt][m][sk][0][2], raw[tt][m][sk][0][3]);
          v.u[2] = cvt_pk_bf16(raw[tt][m][sk][1][0], raw[tt][m][sk][1][1]);
          v.u[3] = cvt_pk_bf16(raw[tt][m][sk][1][2], raw[tt][m][sk][1][3]);
          bx[tt][m][sk] = v.s8;
        }
  }

  const float* Bi  = bias;               // permuted (index g*16+d)
  const float* Bc  = bias + HID;
  const float* Bo  = bias + 2 * HID;
  const float* Wco = bias + 3 * HID;
  const float* Fcb = bias + 4 * HID;     // standard od order

#pragma unroll
  for (int tt = 0; tt < 2; ++tt) {
    const size_t row0 = rbase + tt * 32;

    // ---- Phase 1: 8 GEMM1 h-tiles + gates; H banked in 32 u32 regs ----
    unsigned hbuf[8][2][2];              // [g][m][word]
#pragma unroll
    for (int g = 0; g < 8; ++g) {
      const int p0 = g * 16 + 4 * q;
      f32x4 vbi = *(const f32x4*)(Bi + p0);
      f32x4 vbc = *(const f32x4*)(Bc + p0);
      f32x4 vbo = *(const f32x4*)(Bo + p0);
      f32x4 vwc = *(const f32x4*)(Wco + p0);
      f32x4 acc[3][2];
#pragma unroll
      for (int m = 0; m < 2; ++m) { acc[0][m] = vbi; acc[1][m] = vbc; acc[2][m] = vbo; }
#pragma unroll
      for (int sk = 0; sk < 2; ++sk) {
        short8 ai = *(const short8*)(wf + ((g     ) * 2 + sk) * 512);
        short8 ac = *(const short8*)(wf + ((g +  8) * 2 + sk) * 512);
        short8 ao = *(const short8*)(wf + ((g + 16) * 2 + sk) * 512);
#pragma unroll
        for (int m = 0; m < 2; ++m) {
          acc[0][m] = __builtin_amdgcn_mfma_f32_16x16x32_bf16(ai, bx[tt][m][sk], acc[0][m], 0, 0, 0);
          acc[1][m] = __builtin_amdgcn_mfma_f32_16x16x32_bf16(ac, bx[tt][m][sk], acc[1][m], 0, 0, 0);
          acc[2][m] = __builtin_amdgcn_mfma_f32_16x16x32_bf16(ao, bx[tt][m][sk], acc[2][m], 0, 0, 0);
        }
      }
      // gates -> packed bf16 pairs; D-row d=4q+r -> hid 32s+2gg+8q+4(r>>1)+(r&1)
#pragma unroll
      for (int m = 0; m < 2; ++m) {
        float hw[4];
#pragma unroll
        for (int r = 0; r < 4; ++r) {
          float gi = fsigmoid(acc[0][m][r]);
          float gt = ftanh(acc[1][m][r]);
          float C  = gi * gt;
          float go = fsigmoid(acc[2][m][r] + vwc[r] * C);
          hw[r] = go * ftanh(C);
        }
        hbuf[g][m][0] = cvt_pk_bf16(hw[0], hw[1]);
        hbuf[g][m][1] = cvt_pk_bf16(hw[2], hw[3]);
      }
    }

    // ---- Phase 2: GEMM2 dense block; oacc init = fc bias (folded) ----
    f32x4 oacc[4][2];
#pragma unroll
    for (int t = 0; t < 4; ++t) {
      f32x4 fb = *(const f32x4*)(Fcb + 16 * t + 4 * q);
      oacc[t][0] = fb; oacc[t][1] = fb;
    }
#pragma unroll
    for (int s = 0; s < 4; ++s) {
#pragma unroll
      for (int m = 0; m < 2; ++m) {
        U bu;
        bu.u[0] = hbuf[2 * s][m][0];
        bu.u[1] = hbuf[2 * s + 1][m][0];
        bu.u[2] = hbuf[2 * s][m][1];
        bu.u[3] = hbuf[2 * s + 1][m][1];
#pragma unroll
        for (int t = 0; t < 4; ++t) {
          short8 af = *(const short8*)(ff + (t * 4 + s) * 512);
          oacc[t][m] = __builtin_amdgcn_mfma_f32_16x16x32_bf16(af, bu.s8, oacc[t][m], 0, 0, 0);
        }
      }
    }

    // ---- epilogue: coalesced float4 stores ----
#pragma unroll
    for (int t = 0; t < 4; ++t) {
      const int od0 = 16 * t + 4 * q;
#pragma unroll
      for (int m = 0; m < 2; ++m) {
        *(f32x4*)(out + (row0 + 16 * m + c) * OUT_DIM + od0) = oacc[t][m];
      }
    }
  }
}

extern "C" void kernel_launch(void* const* d_in, const int* in_sizes, int n_in,
                              void* d_out, int out_size, void* d_ws, size_t ws_size,
                              hipStream_t stream) {
  (void)in_sizes; (void)n_in; (void)out_size; (void)ws_size;
  const float* x    = (const float*)d_in[0];
  const float* W_i  = (const float*)d_in[3];
  const float* W_c  = (const float*)d_in[5];
  const float* W_o  = (const float*)d_in[6];
  const float* bg_i = (const float*)d_in[11];
  const float* bg_c = (const float*)d_in[13];
  const float* bg_o = (const float*)d_in[14];
  const float* wc_o = (const float*)d_in[17];
  const float* b_i  = (const float*)d_in[18];
  const float* b_c  = (const float*)d_in[20];
  const float* b_o  = (const float*)d_in[21];
  const float* fc_W = (const float*)d_in[22];
  const float* fc_b = (const float*)d_in[23];

  short* wfrag  = (short*)d_ws;
  short* fcfrag = (short*)((char*)d_ws + FCFRAG_OFF);
  float* bias   = (float*)((char*)d_ws + BIAS_OFF);

  repack_kernel<<<dim3(64), dim3(256), 0, stream>>>(
      W_i, W_c, W_o, fc_W, bg_i, bg_c, bg_o, b_i, b_c, b_o, wc_o, fc_b,
      wfrag, fcfrag, bias);

  const int nwaves = N_ROWS / 64;           // 3125 waves, 2 tiles each
  const int nwg = (nwaves + 3) / 4;         // 782 (256-thread WGs, 4 waves)
  gclstm_fused<<<dim3(nwg), dim3(256), 0, stream>>>(
      x, wfrag, fcfrag, bias, (float*)d_out);
}

// Round 9
// 49.542 us; speedup vs baseline: 1.2746x; 1.2746x over previous
//
#include <hip/hip_runtime.h>

// GCLSTM (K=1 Cheb, H0=C0=0) fused kernel for MI355X — v9.
// Math: i=sig(x@Wi+bi'), t=tanh(x@Wc+bc'), C=i*t, o=sig(x@Wo+bo'+wco*C),
//       out = (o*tanh(C)) @ fcW + fcb.  edge_index/batch/Wg_*/W_f unused.
// v9: VALU-window reduction + wave stagger.
//  - sig(a)*tanh(b) = (e2b-1)*rcp((1+e-a)(1+e2b)): 6 trans/elem (was 8).
//  - weights/biases prescaled by -+log2(e) in repack: exp2 args come
//    straight from MFMA accumulators (no scaling muls).
//  - gate math in f32x4 vector form -> v_pk_* double-pumped fp32.
//  - WG = 64 (1 wave, no barrier, no LDS), 6250 WGs for max dispatch
//    stagger; launch_bounds(64,4) (128 VGPR cap, no spill).

typedef __attribute__((ext_vector_type(8))) short short8;
typedef __attribute__((ext_vector_type(4))) float f32x4;

#define N_ROWS 200000
#define IN_DIM 64
#define HID 128
#define OUT_DIM 64

#define LOG2E 1.44269504f
#define TWOLOG2E 2.88539008f

// ws layout (bytes)
#define WFRAG_ELEMS (24 * 2 * 64 * 8)   // 24576 bf16 = 49152 B
#define FCFRAG_OFF  49152               // WFRAG_ELEMS*2
#define FCFRAG_ELEMS (4 * 4 * 64 * 8)   // 8192 bf16 = 16384 B
#define BIAS_OFF    65536               // floats: si[128],sc[128],so[128],swc[128] (h-permuted, prescaled), fcb[64]

__device__ __forceinline__ short f2bf(float f) {
  unsigned u = __float_as_uint(f);
  u += 0x7FFFu + ((u >> 16) & 1u);   // RNE (repack only)
  return (short)(u >> 16);
}
__device__ __forceinline__ unsigned cvt_pk_bf16(float lo, float hi) {
  unsigned r;
  asm("v_cvt_pk_bf16_f32 %0, %1, %2" : "=v"(r) : "v"(lo), "v"(hi));
  return r;
}
__device__ __forceinline__ float fexp2(float z) { return __builtin_amdgcn_exp2f(z); }
__device__ __forceinline__ float frcp(float z)  { return __builtin_amdgcn_rcpf(z); }
// permuted global hid for GEMM1 tile g (0..7), D-row d (0..15)
__device__ __forceinline__ int hperm(int g, int d) {
  return 32 * (g >> 1) + 2 * (g & 1) + 8 * (d >> 2) + 4 * ((d >> 1) & 1) + (d & 1);
}

// ---- repack: weights -> bf16 MFMA A-fragments (PRESCALED), biases fp32 ----
__global__ void repack_kernel(const float* __restrict__ W_i, const float* __restrict__ W_c,
                              const float* __restrict__ W_o, const float* __restrict__ fc_W,
                              const float* __restrict__ bg_i, const float* __restrict__ bg_c,
                              const float* __restrict__ bg_o,
                              const float* __restrict__ b_i, const float* __restrict__ b_c,
                              const float* __restrict__ b_o, const float* __restrict__ wc_o,
                              const float* __restrict__ fc_b,
                              short* __restrict__ wfrag, short* __restrict__ fcfrag,
                              float* __restrict__ bias) {
  int tid = blockIdx.x * blockDim.x + threadIdx.x;
  const int total1 = WFRAG_ELEMS;
  const int total2 = FCFRAG_ELEMS;
  for (int e = tid; e < total1 + total2 + HID + OUT_DIM; e += gridDim.x * blockDim.x) {
    if (e < total1) {
      // A-frag of GEMM1: D-row cidx of tile g, k=32s+8q+j, PERMUTED h, PRESCALED
      int j = e & 7, lane = (e >> 3) & 63, s = (e >> 9) & 1, t = e >> 10;
      int q = lane >> 4, cidx = lane & 15;
      int gate = t >> 3;                       // 0:W_i 1:W_c 2:W_o
      int g = t & 7;
      int h = hperm(g, cidx);
      int feat = 32 * s + 8 * q + j;
      const float* W = (gate == 0) ? W_i : ((gate == 1) ? W_c : W_o);
      float scale = (gate == 1) ? TWOLOG2E : -LOG2E;
      wfrag[e] = f2bf(W[feat * HID + h] * scale);
    } else if (e < total1 + total2) {
      // A-frag of GEMM2: A = fc_W^T (64x128), STANDARD hid = 32s+8q+j
      int e2 = e - total1;
      int j = e2 & 7, lane = (e2 >> 3) & 63, s = (e2 >> 9) & 3, t = e2 >> 11;
      int q = lane >> 4, cidx = lane & 15;
      int od = 16 * t + cidx;
      int hid = 32 * s + 8 * q + j;
      fcfrag[e2] = f2bf(fc_W[hid * OUT_DIM + od]);
    } else if (e < total1 + total2 + HID) {
      int p = e - total1 - total2;             // permuted storage index g*16+d
      int h = hperm(p >> 4, p & 15);
      bias[p]           = -LOG2E  * (bg_i[h] + b_i[h]);
      bias[HID + p]     = TWOLOG2E * (bg_c[h] + b_c[h]);
      bias[2 * HID + p] = -LOG2E  * (bg_o[h] + b_o[h]);
      bias[3 * HID + p] = -LOG2E  * wc_o[h];
    } else {
      int h2 = e - total1 - total2 - HID;
      bias[4 * HID + h2] = fc_b[h2];
    }
  }
}

// ---- fused main kernel: 1 wave per WG, 32 rows, no LDS, no barriers ----
__global__ __launch_bounds__(64, 4) void gclstm_fused(
    const float* __restrict__ x, const short* __restrict__ wfrag,
    const short* __restrict__ fcfrag, const float* __restrict__ bias,
    float* __restrict__ out) {
  const int lane = threadIdx.x;          // 0..63
  const int wid = blockIdx.x;            // 0..6249
  const size_t row0 = (size_t)wid * 32;
  const int q = lane >> 4, c = lane & 15;
  const short* wf = wfrag + lane * 8;
  const short* ff = fcfrag + lane * 8;

  union U { unsigned u[4]; short8 s8; };

  // x B-fragments: B = x^T; lane supplies col (row row0+16m+c), k=32sk+8q+j
  short8 bx[2][2];
#pragma unroll
  for (int m = 0; m < 2; ++m) {
    const float* xr = x + (row0 + 16 * m + c) * IN_DIM + 8 * q;
#pragma unroll
    for (int sk = 0; sk < 2; ++sk) {
      f32x4 f0 = *(const f32x4*)(xr + 32 * sk);
      f32x4 f1 = *(const f32x4*)(xr + 32 * sk + 4);
      U v;
      v.u[0] = cvt_pk_bf16(f0[0], f0[1]);
      v.u[1] = cvt_pk_bf16(f0[2], f0[3]);
      v.u[2] = cvt_pk_bf16(f1[0], f1[1]);
      v.u[3] = cvt_pk_bf16(f1[2], f1[3]);
      bx[m][sk] = v.s8;
    }
  }

  const float* Si  = bias;               // prescaled, permuted (index g*16+d)
  const float* Sc  = bias + HID;
  const float* So  = bias + 2 * HID;
  const float* Swc = bias + 3 * HID;
  const float* Fcb = bias + 4 * HID;     // standard od order

  // ---- Phase 1: 8 GEMM1 h-tiles + gates; H banked in 32 u32 regs ----
  unsigned hbuf[8][2][2];                // [g][m][word]
#pragma unroll
  for (int g = 0; g < 8; ++g) {
    const int p0 = g * 16 + 4 * q;
    f32x4 vbi = *(const f32x4*)(Si + p0);
    f32x4 vbc = *(const f32x4*)(Sc + p0);
    f32x4 vbo = *(const f32x4*)(So + p0);
    f32x4 vwc = *(const f32x4*)(Swc + p0);
    f32x4 acc[3][2];
#pragma unroll
    for (int m = 0; m < 2; ++m) { acc[0][m] = vbi; acc[1][m] = vbc; acc[2][m] = vbo; }
#pragma unroll
    for (int sk = 0; sk < 2; ++sk) {
      short8 ai = *(const short8*)(wf + ((g     ) * 2 + sk) * 512);
      short8 ac = *(const short8*)(wf + ((g +  8) * 2 + sk) * 512);
      short8 ao = *(const short8*)(wf + ((g + 16) * 2 + sk) * 512);
#pragma unroll
      for (int m = 0; m < 2; ++m) {
        acc[0][m] = __builtin_amdgcn_mfma_f32_16x16x32_bf16(ai, bx[m][sk], acc[0][m], 0, 0, 0);
        acc[1][m] = __builtin_amdgcn_mfma_f32_16x16x32_bf16(ac, bx[m][sk], acc[1][m], 0, 0, 0);
        acc[2][m] = __builtin_amdgcn_mfma_f32_16x16x32_bf16(ao, bx[m][sk], acc[2][m], 0, 0, 0);
      }
    }
    // gates (prescaled args): ei=e^-zi, ec=e^2zc ->
    //   C = (ec-1)*rcp((1+ei)(1+ec));  s = -log2e*(zo+wc*C) (via prescale);
    //   e2 = e^2C; H = (e2-1)*rcp((1+eo)(1+e2)).  f32x4 form -> v_pk_* ops.
#pragma unroll
    for (int m = 0; m < 2; ++m) {
      f32x4 ei, ec;
#pragma unroll
      for (int r = 0; r < 4; ++r) { ei[r] = fexp2(acc[0][m][r]); ec[r] = fexp2(acc[1][m][r]); }
      f32x4 den1 = (ei + 1.0f) * (ec + 1.0f);
      f32x4 rd1;
#pragma unroll
      for (int r = 0; r < 4; ++r) rd1[r] = frcp(den1[r]);
      f32x4 C = (ec - 1.0f) * rd1;
      f32x4 s2 = acc[2][m] + vwc * C;          // pk fma (prescaled o-arg)
      f32x4 t2 = C * TWOLOG2E;
      f32x4 eo, e2;
#pragma unroll
      for (int r = 0; r < 4; ++r) { eo[r] = fexp2(s2[r]); e2[r] = fexp2(t2[r]); }
      f32x4 den2 = (eo + 1.0f) * (e2 + 1.0f);
      f32x4 rd2;
#pragma unroll
      for (int r = 0; r < 4; ++r) rd2[r] = frcp(den2[r]);
      f32x4 H = (e2 - 1.0f) * rd2;
      hbuf[g][m][0] = cvt_pk_bf16(H[0], H[1]);
      hbuf[g][m][1] = cvt_pk_bf16(H[2], H[3]);
    }
  }

  // ---- Phase 2: GEMM2 dense block; oacc init = fc bias (folded) ----
  f32x4 oacc[4][2];
#pragma unroll
  for (int t = 0; t < 4; ++t) {
    f32x4 fb = *(const f32x4*)(Fcb + 16 * t + 4 * q);
    oacc[t][0] = fb; oacc[t][1] = fb;
  }
#pragma unroll
  for (int s = 0; s < 4; ++s) {
#pragma unroll
    for (int m = 0; m < 2; ++m) {
      U bu;
      bu.u[0] = hbuf[2 * s][m][0];
      bu.u[1] = hbuf[2 * s + 1][m][0];
      bu.u[2] = hbuf[2 * s][m][1];
      bu.u[3] = hbuf[2 * s + 1][m][1];
#pragma unroll
      for (int t = 0; t < 4; ++t) {
        short8 af = *(const short8*)(ff + (t * 4 + s) * 512);
        oacc[t][m] = __builtin_amdgcn_mfma_f32_16x16x32_bf16(af, bu.s8, oacc[t][m], 0, 0, 0);
      }
    }
  }

  // ---- epilogue: coalesced float4 stores ----
#pragma unroll
  for (int t = 0; t < 4; ++t) {
    const int od0 = 16 * t + 4 * q;
#pragma unroll
    for (int m = 0; m < 2; ++m) {
      *(f32x4*)(out + (row0 + 16 * m + c) * OUT_DIM + od0) = oacc[t][m];
    }
  }
}

extern "C" void kernel_launch(void* const* d_in, const int* in_sizes, int n_in,
                              void* d_out, int out_size, void* d_ws, size_t ws_size,
                              hipStream_t stream) {
  (void)in_sizes; (void)n_in; (void)out_size; (void)ws_size;
  const float* x    = (const float*)d_in[0];
  const float* W_i  = (const float*)d_in[3];
  const float* W_c  = (const float*)d_in[5];
  const float* W_o  = (const float*)d_in[6];
  const float* bg_i = (const float*)d_in[11];
  const float* bg_c = (const float*)d_in[13];
  const float* bg_o = (const float*)d_in[14];
  const float* wc_o = (const float*)d_in[17];
  const float* b_i  = (const float*)d_in[18];
  const float* b_c  = (const float*)d_in[20];
  const float* b_o  = (const float*)d_in[21];
  const float* fc_W = (const float*)d_in[22];
  const float* fc_b = (const float*)d_in[23];

  short* wfrag  = (short*)d_ws;
  short* fcfrag = (short*)((char*)d_ws + FCFRAG_OFF);
  float* bias   = (float*)((char*)d_ws + BIAS_OFF);

  repack_kernel<<<dim3(64), dim3(256), 0, stream>>>(
      W_i, W_c, W_o, fc_W, bg_i, bg_c, bg_o, b_i, b_c, b_o, wc_o, fc_b,
      wfrag, fcfrag, bias);

  const int nwg = N_ROWS / 32;              // 6250 single-wave WGs
  gclstm_fused<<<dim3(nwg), dim3(64), 0, stream>>>(
      x, wfrag, fcfrag, bias, (float*)d_out);
}